// Round 14
// baseline (910.497 us; speedup 1.0000x reference)
//
#include <hip/hip_runtime.h>
#include <stdint.h>
#include <math.h>

#define D_CAT  1024
#define R_TR   64
#define RR     4096      // R*R
#define NDRAWS 2048
#define KMODES 8

struct CorePtrs { const float* p[KMODES]; };

typedef __attribute__((ext_vector_type(8))) __bf16 bf16x8;
typedef __attribute__((ext_vector_type(4))) float  f32x4;
typedef unsigned int u32;

union BF8 { ushort u[8]; bf16x8 v; };

// async global->LDS 16B copy: LDS dest is wave-uniform base + lane*16
static __device__ inline void async_cp16(const void* g, void* l) {
  __builtin_amdgcn_global_load_lds(
      (const __attribute__((address_space(1))) u32*)g,
      (__attribute__((address_space(3))) u32*)l, 16, 0, 0);
}

// ---------------- threefry2x32 (JAX-exact, 20 rounds) ----------------
static __host__ __device__ inline uint32_t rotl32(uint32_t x, int r) {
  return (x << r) | (x >> (32 - r));
}
static __host__ __device__ inline void tf2x32(uint32_t k1, uint32_t k2,
                                              uint32_t x0, uint32_t x1,
                                              uint32_t& o0, uint32_t& o1) {
  uint32_t ks0 = k1, ks1 = k2, ks2 = k1 ^ k2 ^ 0x1BD11BDAu;
  x0 += ks0; x1 += ks1;
  x0 += x1; x1 = rotl32(x1, 13); x1 ^= x0;
  x0 += x1; x1 = rotl32(x1, 15); x1 ^= x0;
  x0 += x1; x1 = rotl32(x1, 26); x1 ^= x0;
  x0 += x1; x1 = rotl32(x1, 6);  x1 ^= x0;
  x0 += ks1; x1 += ks2 + 1u;
  x0 += x1; x1 = rotl32(x1, 17); x1 ^= x0;
  x0 += x1; x1 = rotl32(x1, 29); x1 ^= x0;
  x0 += x1; x1 = rotl32(x1, 16); x1 ^= x0;
  x0 += x1; x1 = rotl32(x1, 24); x1 ^= x0;
  x0 += ks2; x1 += ks0 + 2u;
  x0 += x1; x1 = rotl32(x1, 13); x1 ^= x0;
  x0 += x1; x1 = rotl32(x1, 15); x1 ^= x0;
  x0 += x1; x1 = rotl32(x1, 26); x1 ^= x0;
  x0 += x1; x1 = rotl32(x1, 6);  x1 ^= x0;
  x0 += ks0; x1 += ks1 + 3u;
  x0 += x1; x1 = rotl32(x1, 17); x1 ^= x0;
  x0 += x1; x1 = rotl32(x1, 29); x1 ^= x0;
  x0 += x1; x1 = rotl32(x1, 16); x1 ^= x0;
  x0 += x1; x1 = rotl32(x1, 24); x1 ^= x0;
  x0 += ks1; x1 += ks2 + 4u;
  x0 += x1; x1 = rotl32(x1, 13); x1 ^= x0;
  x0 += x1; x1 = rotl32(x1, 15); x1 ^= x0;
  x0 += x1; x1 = rotl32(x1, 26); x1 ^= x0;
  x0 += x1; x1 = rotl32(x1, 6);  x1 ^= x0;
  x0 += ks2; x1 += ks0 + 5u;
  o0 = x0; o1 = x1;
}

// fast softplus: max(x,0)+log(1+exp(-|x|)) via v_exp_f32/v_log_f32.
static __device__ inline float softplus_fast(float x) {
  float e = __expf(-fabsf(x));
  return fmaxf(x, 0.0f) + __logf(1.0f + e);
}

static __device__ inline unsigned short f32_bf16(float f) {  // RNE
  uint32_t u = __float_as_uint(f);
  u += 0x7fffu + ((u >> 16) & 1u);
  return (unsigned short)(u >> 16);
}

// gumbel for flat element e under key (k1,k2), partitionable path
static __device__ inline float gumbel_at(uint32_t k1, uint32_t k2, uint32_t e) {
  uint32_t o0, o1;
  tf2x32(k1, k2, 0u, e, o0, o1);
  uint32_t bits = o0 ^ o1;
  float f = __uint_as_float((bits >> 9) | 0x3F800000u) - 1.0f;
  float u = (f > 0.0f) ? f : 1.17549435e-38f;   // finfo(f32).tiny
  return -logf(-logf(u));
}

// ---------------- kernels ----------------

__global__ void k_sentinel(float* out, int n) {
  int i = blockIdx.x * 256 + threadIdx.x;
  if (i < n) out[i] = -12288.0f;  // ws-too-small marker
}

// partial column sums of softplus(core_i): grid 8*256 (4 d-rows each)
__global__ __launch_bounds__(256) void k_spart(CorePtrs cp, float* __restrict__ Spart) {
  const int bid = blockIdx.x, tid = threadIdx.x;
  const int i = bid >> 8, c = bid & 255;
  const float* src = cp.p[i] + (size_t)c * 4 * RR;
  float acc[16];
#pragma unroll
  for (int k = 0; k < 16; ++k) acc[k] = 0.0f;
#pragma unroll
  for (int d = 0; d < 4; ++d) {
    const float* row = src + (size_t)d * RR;
#pragma unroll
    for (int k = 0; k < 16; ++k)
      acc[k] += softplus_fast(row[tid + k * 256]);
  }
  float* dst = Spart + (size_t)bid * RR;
#pragma unroll
  for (int k = 0; k < 16; ++k) dst[tid + k * 256] = acc[k];
}

// reduce 256 f32 partials -> S[i][rr] f64: grid 128, block 256
__global__ __launch_bounds__(256) void k_sreduce(const float* __restrict__ Spart,
                                                 double* __restrict__ S) {
  const int idx = blockIdx.x * 256 + threadIdx.x;   // 0..32767
  const int i = idx >> 12, rr = idx & 4095;
  const float* p = Spart + ((size_t)i << 20) + rr;  // i*256*4096
  double a0 = 0.0, a1 = 0.0, a2 = 0.0, a3 = 0.0;
  for (int c = 0; c < 256; c += 4) {
    a0 += (double)p[(size_t)(c + 0) * RR];
    a1 += (double)p[(size_t)(c + 1) * RR];
    a2 += (double)p[(size_t)(c + 2) * RR];
    a3 += (double)p[(size_t)(c + 3) * RR];
  }
  S[idx] = (a0 + a1) + (a2 + a3);
}

// heads chain + log(trace(norm)): 1 block, 256 threads.
__global__ __launch_bounds__(256) void k_heads(const double* __restrict__ S,
                                               double* __restrict__ heads,
                                               double* __restrict__ misc) {
  __shared__ double cur[RR];
  __shared__ double Sm[RR];
  __shared__ double tbuf[64];
  const int tid = threadIdx.x;
  const int bcol = tid & 63;
  const int a0 = tid >> 6;
#pragma unroll
  for (int k = 0; k < 16; ++k) {
    int p = tid + k * 256;
    double v = S[p];
    cur[p] = v;
    heads[p] = v;          // slot 0 = heads[1] = S0
  }
  __syncthreads();
  for (int m = 1; m <= 6; ++m) {
#pragma unroll
    for (int k = 0; k < 16; ++k) {
      int p = tid + k * 256;
      Sm[p] = S[(size_t)m * RR + p];
    }
    __syncthreads();
    double acc[16];
#pragma unroll
    for (int k = 0; k < 16; ++k) acc[k] = 0.0;
    for (int c = 0; c < 64; ++c) {
      double s = Sm[c * 64 + bcol];
#pragma unroll
      for (int k = 0; k < 16; ++k)
        acc[k] = fma(cur[(a0 + 4 * k) * 64 + c], s, acc[k]);
    }
    __syncthreads();
#pragma unroll
    for (int k = 0; k < 16; ++k) {
      int p = tid + k * 256;     // == (a0+4k)*64 + bcol
      cur[p] = acc[k];
      heads[(size_t)m * RR + p] = acc[k];
    }
    __syncthreads();
  }
  // trace(norm) = trace(cur @ S7), S7 staged in LDS
#pragma unroll
  for (int k = 0; k < 16; ++k) {
    int p = tid + k * 256;
    Sm[p] = S[(size_t)7 * RR + p];
  }
  __syncthreads();
  if (tid < 64) {
    double acc = 0.0;
    for (int c = 0; c < 64; ++c)
      acc = fma(cur[tid * 64 + c], Sm[c * 64 + tid], acc);
    tbuf[tid] = acc;
  }
  __syncthreads();
  if (tid == 0) {
    double tr = 0.0;
    for (int a = 0; a < 64; ++a) tr += tbuf[a];
    misc[0] = log(tr);
  }
}

// step 0 weights from RAW core (inline softplus)
__global__ __launch_bounds__(256) void k_w0(const float* __restrict__ raw,
                                            const double* __restrict__ head7,
                                            float* __restrict__ W) {
  const int tid = threadIdx.x;
  const int lane = tid & 63;
  const int n = blockIdx.x * 4 + (tid >> 6);
  const float* crow = raw + (size_t)n * RR;
  double acc = 0.0;
  for (int q = lane; q < RR; q += 64)
    acc = fma((double)softplus_fast(crow[q]), head7[(q & 63) * 64 + (q >> 6)], acc);
  for (int m = 32; m; m >>= 1) acc += __shfl_xor(acc, m);
  if (lane == 0) W[n] = (float)acc;
}

// FUSED: blocks 0..4095 = softplus(core_j)->Bh/Bl split;
//        blocks 4096..4607 = Mt build (MFMA w/ head, or direct transpose if !useHead)
__global__ __launch_bounds__(256) void k_spmt(const float* __restrict__ src,
                                              ushort* __restrict__ Bh,
                                              ushort* __restrict__ Bl,
                                              const float* __restrict__ tail,
                                              const double* __restrict__ head, int useHead,
                                              ushort* __restrict__ Ah,
                                              ushort* __restrict__ Al) {
  __shared__ alignas(16) float smem[4176];   // 16.7KB: mt2 hT(16KB) or mtid 64x65 f32
  const int bid = blockIdx.x, tid = threadIdx.x;
  if (bid < 4096) {
    // ---- softplus split path ----
    const size_t i4 = ((size_t)bid * 256 + tid) * 4;
    float4 v = *(const float4*)(src + i4);
    const float ov[4] = {softplus_fast(v.x), softplus_fast(v.y),
                         softplus_fast(v.z), softplus_fast(v.w)};
    ushort h4[4], l4[4];
#pragma unroll
    for (int q = 0; q < 4; ++q) {
      ushort h = f32_bf16(ov[q]);
      float hf = __uint_as_float((uint32_t)h << 16);
      h4[q] = h;
      l4[q] = f32_bf16(ov[q] - hf);
    }
    *(ushort4*)(Bh + i4) = make_ushort4(h4[0], h4[1], h4[2], h4[3]);
    *(ushort4*)(Bl + i4) = make_ushort4(l4[0], l4[1], l4[2], l4[3]);
    return;
  }
  const int blk = bid - 4096;   // 0..511
  if (useHead) {
    // ---- mt2: Mt[B,k*64+i] = sum_c tail[B,i,c]*head[c,k] via bf16 3-pass ----
    ushort (*hT)[4096] = (ushort(*)[4096])smem;
#pragma unroll
    for (int rep = 0; rep < 16; ++rep) {
      int i = tid + rep * 256;
      float v = (float)head[(i & 63) * 64 + (i >> 6)];
      ushort h = f32_bf16(v);
      float hf = __uint_as_float((uint32_t)h << 16);
      int dst = (i & 0xFC0) | (((((i >> 3) & 7) ^ ((i >> 6) & 7)) << 3)) | (i & 7);
      hT[0][dst] = h;
      hT[1][dst] = f32_bf16(v - hf);
    }
    __syncthreads();
    const int w = tid >> 6, l = tid & 63;
    const int B = blk * 4 + w;
    const float* tb = tail + (size_t)B * RR;
    const int lrow = l & 15, kg = l >> 4;
    ushort* ah_out = Ah + (size_t)B * RR;
    ushort* al_out = Al + (size_t)B * RR;
    for (int it = 0; it < 4; ++it) {
      BF8 afh[2], afl[2];
#pragma unroll
      for (int kt = 0; kt < 2; ++kt) {
        const float* s2 = tb + (it * 16 + lrow) * 64 + kt * 32 + kg * 8;
        float4 v0 = *(const float4*)s2;
        float4 v1 = *(const float4*)(s2 + 4);
        float vv[8] = {v0.x, v0.y, v0.z, v0.w, v1.x, v1.y, v1.z, v1.w};
#pragma unroll
        for (int q = 0; q < 8; ++q) {
          ushort h = f32_bf16(vv[q]);
          float hf = __uint_as_float((uint32_t)h << 16);
          afh[kt].u[q] = h;
          afl[kt].u[q] = f32_bf16(vv[q] - hf);
        }
      }
#pragma unroll
      for (int kt2 = 0; kt2 < 4; ++kt2) {
        f32x4 hh = (f32x4)0.0f, sm = (f32x4)0.0f;
#pragma unroll
        for (int kt = 0; kt < 2; ++kt) {
          int rowB = kt2 * 16 + lrow;
          int kcA  = kt * 4 + kg;
          int off  = rowB * 64 + ((kcA ^ (rowB & 7)) << 3);
          bf16x8 bh = *(const bf16x8*)&hT[0][off];
          bf16x8 bl = *(const bf16x8*)&hT[1][off];
          hh = __builtin_amdgcn_mfma_f32_16x16x32_bf16(afh[kt].v, bh, hh, 0, 0, 0);
          sm = __builtin_amdgcn_mfma_f32_16x16x32_bf16(afh[kt].v, bl, sm, 0, 0, 0);
          sm = __builtin_amdgcn_mfma_f32_16x16x32_bf16(afl[kt].v, bh, sm, 0, 0, 0);
        }
        ushort h4[4], l4[4];
#pragma unroll
        for (int q = 0; q < 4; ++q) {
          float v = hh[q] + sm[q];
          ushort h = f32_bf16(v);
          float hf = __uint_as_float((uint32_t)h << 16);
          h4[q] = h;
          l4[q] = f32_bf16(v - hf);
        }
        int o = (kt2 * 16 + lrow) * 64 + it * 16 + kg * 4;   // Mt = k*64 + i
        *(ushort4*)(ah_out + o) = make_ushort4(h4[0], h4[1], h4[2], h4[3]);
        *(ushort4*)(al_out + o) = make_ushort4(l4[0], l4[1], l4[2], l4[3]);
      }
    }
  } else {
    // ---- mtid: Mt[B,k*64+i] = tail[B,i,k] (head==I), pure transpose+split ----
    float* tl = smem;   // [64][65] padded
    for (int d = 0; d < 4; ++d) {
      const int B = blk * 4 + d;
      const float* tb = tail + (size_t)B * RR;
      ushort* ah_out = Ah + (size_t)B * RR;
      ushort* al_out = Al + (size_t)B * RR;
      __syncthreads();
#pragma unroll
      for (int r = 0; r < 4; ++r) {
        int p = tid * 4 + r * 1024;
        int i = p >> 6, k = p & 63;
        float4 v = *(const float4*)(tb + p);
        tl[i * 65 + k + 0] = v.x; tl[i * 65 + k + 1] = v.y;
        tl[i * 65 + k + 2] = v.z; tl[i * 65 + k + 3] = v.w;
      }
      __syncthreads();
#pragma unroll
      for (int r = 0; r < 4; ++r) {
        int p = tid * 4 + r * 1024;
        int k = p >> 6, i0 = p & 63;
        ushort h4[4], l4[4];
#pragma unroll
        for (int q = 0; q < 4; ++q) {
          float m = tl[(i0 + q) * 65 + k];
          ushort h = f32_bf16(m);
          float hf = __uint_as_float((uint32_t)h << 16);
          h4[q] = h;
          l4[q] = f32_bf16(m - hf);
        }
        *(ushort4*)(ah_out + p) = make_ushort4(h4[0], h4[1], h4[2], h4[3]);
        *(ushort4*)(al_out + p) = make_ushort4(l4[0], l4[1], l4[2], l4[3]);
      }
    }
  }
}

// W-GEMM with FUSED gumbel-argmax epilogue: never materializes W.
// Per block (bn,bb): 64x64 tile of w stays in regs; epilogue computes
// v = gumbel + log(w) per element and reduces to per-row partials
// P[(bb*64+row)*16 + bn] = (best v, argmax col). XCD-region swizzle.
__global__ __launch_bounds__(256) void k_wgemm(const ushort* __restrict__ Ah,
                                               const ushort* __restrict__ Al,
                                               const ushort* __restrict__ Bh,
                                               const ushort* __restrict__ Bl,
                                               uint32_t key1, uint32_t key2,
                                               float2* __restrict__ P) {
  __shared__ ushort lds[2][4 * 4096];
  const int tid = threadIdx.x;
  const int L = blockIdx.x;            // 0..511
  const int x = L & 7, j = L >> 3;
  const int bn = (x & 1) * 8 + (j & 7);
  const int bb = (x >> 1) * 8 + (j >> 3);
  const int w = tid >> 6, l = tid & 63;

  const int srow = l >> 3;
  const int skc  = l & 7;
  const ushort* gbase;
  {
    const ushort* bases[4] = {Ah + (size_t)bb * 64 * RR, Al + (size_t)bb * 64 * RR,
                              Bh + (size_t)bn * 64 * RR, Bl + (size_t)bn * 64 * RR};
    gbase = bases[w] + (size_t)srow * RR + (size_t)((skc ^ srow) * 8);
  }

  const int wm = (w >> 1) * 32, wn = (w & 1) * 32;
  const int lrow = l & 15;
  const int kg   = l >> 4;

  f32x4 acc_hh[2][2], acc_sm[2][2], hht[2][2];
#pragma unroll
  for (int mt = 0; mt < 2; ++mt)
#pragma unroll
    for (int nt = 0; nt < 2; ++nt) {
      acc_hh[mt][nt] = (f32x4)0.0f;
      acc_sm[mt][nt] = (f32x4)0.0f;
      hht[mt][nt]    = (f32x4)0.0f;
    }

  int roffA[2][2], roffB[2][2];
#pragma unroll
  for (int mt = 0; mt < 2; ++mt)
#pragma unroll
    for (int kt = 0; kt < 2; ++kt) {
      int rowA = wm + mt * 16 + lrow;
      int kcA  = kt * 4 + kg;
      roffA[mt][kt] = rowA * 64 + ((kcA ^ (rowA & 7)) << 3);
      int rowB = wn + mt * 16 + lrow;
      roffB[mt][kt] = rowB * 64 + ((kcA ^ (rowB & 7)) << 3);
    }

#pragma unroll
  for (int q = 0; q < 8; ++q)
    async_cp16(gbase + (size_t)q * 8 * RR, &lds[0][w * 4096 + q * 512]);

  for (int t = 0; t < 64; ++t) {
    const int bf = t & 1;
    __syncthreads();
    if (t < 63) {
      const int koff = (t + 1) * 64;
#pragma unroll
      for (int q = 0; q < 8; ++q)
        async_cp16(gbase + (size_t)q * 8 * RR + koff,
                   &lds[bf ^ 1][w * 4096 + q * 512]);
    }
    const ushort* L2 = lds[bf];
#pragma unroll
    for (int kt = 0; kt < 2; ++kt) {
      bf16x8 ah[2], al[2], bh[2], bl[2];
#pragma unroll
      for (int mt = 0; mt < 2; ++mt) {
        ah[mt] = *(const bf16x8*)&L2[0 * 4096 + roffA[mt][kt]];
        al[mt] = *(const bf16x8*)&L2[1 * 4096 + roffA[mt][kt]];
      }
#pragma unroll
      for (int nt = 0; nt < 2; ++nt) {
        bh[nt] = *(const bf16x8*)&L2[2 * 4096 + roffB[nt][kt]];
        bl[nt] = *(const bf16x8*)&L2[3 * 4096 + roffB[nt][kt]];
      }
#pragma unroll
      for (int mt = 0; mt < 2; ++mt)
#pragma unroll
        for (int nt = 0; nt < 2; ++nt) {
          acc_hh[mt][nt] = __builtin_amdgcn_mfma_f32_16x16x32_bf16(ah[mt], bh[nt], acc_hh[mt][nt], 0, 0, 0);
          acc_sm[mt][nt] = __builtin_amdgcn_mfma_f32_16x16x32_bf16(ah[mt], bl[nt], acc_sm[mt][nt], 0, 0, 0);
          acc_sm[mt][nt] = __builtin_amdgcn_mfma_f32_16x16x32_bf16(al[mt], bh[nt], acc_sm[mt][nt], 0, 0, 0);
        }
    }
    if ((t & 15) == 15) {
#pragma unroll
      for (int mt = 0; mt < 2; ++mt)
#pragma unroll
        for (int nt = 0; nt < 2; ++nt) {
          hht[mt][nt] += acc_hh[mt][nt];
          acc_hh[mt][nt] = (f32x4)0.0f;
        }
    }
  }

  // ---- fused epilogue: per-row gumbel-argmax partials ----
  __syncthreads();                       // LDS reuse as scratch
  float2* sc = (float2*)lds;             // [64 rows][2 halves]
  float bv[8]; int bi[8];
#pragma unroll
  for (int mt = 0; mt < 2; ++mt)
#pragma unroll
    for (int q = 0; q < 4; ++q) {
      const int s8 = mt * 4 + q;
      bv[s8] = -3.4e38f; bi[s8] = 0x7fffffff;
#pragma unroll
      for (int nt = 0; nt < 2; ++nt) {
        float wv = hht[mt][nt][q] + acc_sm[mt][nt][q];
        int gr = bb * 64 + wm + mt * 16 + kg * 4 + q;
        int gc = bn * 64 + wn + nt * 16 + lrow;
        float v = gumbel_at(key1, key2, (uint32_t)(gr * D_CAT + gc))
                + logf(fmaxf(wv, 1e-30f));
        if (v > bv[s8] || (v == bv[s8] && gc < bi[s8])) { bv[s8] = v; bi[s8] = gc; }
      }
    }
  // reduce across the 16 lrow lanes (xor masks 1..8 keep kg group)
  for (int m = 1; m < 16; m <<= 1) {
#pragma unroll
    for (int s8 = 0; s8 < 8; ++s8) {
      float ov = __shfl_xor(bv[s8], m);
      int   oi = __shfl_xor(bi[s8], m);
      if (ov > bv[s8] || (ov == bv[s8] && oi < bi[s8])) { bv[s8] = ov; bi[s8] = oi; }
    }
  }
  if ((l & 15) == 0) {
#pragma unroll
    for (int mt = 0; mt < 2; ++mt)
#pragma unroll
      for (int q = 0; q < 4; ++q) {
        int r = wm + mt * 16 + kg * 4 + q;
        sc[r * 2 + (wn >> 5)] = make_float2(bv[mt * 4 + q],
                                            __int_as_float(bi[mt * 4 + q]));
      }
  }
  __syncthreads();
  if (tid < 64) {
    float2 a = sc[tid * 2], b2 = sc[tid * 2 + 1];
    float av = a.x;  int ai = __float_as_int(a.y);
    float bvv = b2.x; int bii = __float_as_int(b2.y);
    if (bvv > av || (bvv == av && bii < ai)) { av = bvv; ai = bii; }
    P[(size_t)(bb * 64 + tid) * 16 + bn] = make_float2(av, __int_as_float(ai));
  }
}

// FUSED sample + tail-update: one block per draw.
// Phase 1: argmax from 16 wgemm partials (useW=0) or full shared W row (useW=1).
// Phase 2: tail[b] = C[m] @ tail[b] via MFMA 4-pass (or softplus-copy if first).
__global__ __launch_bounds__(256) void k_samptail(const float* __restrict__ W,
                                                  const float2* __restrict__ P, int useW,
                                                  uint32_t key1, uint32_t key2,
                                                  float* __restrict__ out, int mode_j,
                                                  const float* __restrict__ raw,
                                                  const ushort* __restrict__ Bh,
                                                  const ushort* __restrict__ Bl,
                                                  float* __restrict__ tail, int first) {
  __shared__ float sv[4];
  __shared__ int   si[4];
  __shared__ int   s_m;
  __shared__ alignas(16) ushort Th[4096];
  __shared__ alignas(16) ushort Tl[4096];
  const int b = blockIdx.x, tid = threadIdx.x;

  // ---- phase 1 ----
  if (useW) {
    const float* wrow = W;   // shared row (step 0)
    float best = -3.4e38f; int bidx = 0x7fffffff;
    for (int k = 0; k < 4; ++k) {
      int n = tid + k * 256;
      float lg = logf(fmaxf(wrow[n], 1e-30f));
      float v = gumbel_at(key1, key2, (uint32_t)(b * D_CAT + n)) + lg;
      if (v > best || (v == best && n < bidx)) { best = v; bidx = n; }
    }
    for (int m = 32; m; m >>= 1) {
      float ov = __shfl_xor(best, m);
      int   oi = __shfl_xor(bidx, m);
      if (ov > best || (ov == best && oi < bidx)) { best = ov; bidx = oi; }
    }
    if ((tid & 63) == 0) { sv[tid >> 6] = best; si[tid >> 6] = bidx; }
    __syncthreads();
    if (tid == 0) {
      for (int t = 1; t < 4; ++t)
        if (sv[t] > best || (sv[t] == best && si[t] < bidx)) { best = sv[t]; bidx = si[t]; }
      s_m = bidx;
      out[b * KMODES + mode_j] = (float)bidx;
    }
    __syncthreads();
  } else {
    if (tid < 16) {
      float2 p = P[(size_t)b * 16 + tid];
      float v = p.x; int ix = __float_as_int(p.y);
      for (int m = 1; m < 16; m <<= 1) {
        float ov = __shfl_xor(v, m);
        int   oi = __shfl_xor(ix, m);
        if (ov > v || (ov == v && oi < ix)) { v = ov; ix = oi; }
      }
      if (tid == 0) {
        s_m = ix;
        out[b * KMODES + mode_j] = (float)ix;
      }
    }
    __syncthreads();
  }
  const int m = s_m;
  float* trow = tail + (size_t)b * RR;

  // ---- phase 2: tail update ----
  if (first) {
    const float* crow = raw + (size_t)m * RR;
#pragma unroll
    for (int r = 0; r < 4; ++r) {
      float4 v = *(const float4*)(crow + tid * 4 + r * 1024);
      float4 o;
      o.x = softplus_fast(v.x); o.y = softplus_fast(v.y);
      o.z = softplus_fast(v.z); o.w = softplus_fast(v.w);
      *(float4*)(trow + tid * 4 + r * 1024) = o;
    }
    return;
  }
  const ushort* ch = Bh + (size_t)m * RR;
  const ushort* cl = Bl + (size_t)m * RR;

  // transpose+split old tail into Th/Tl [k][c], chunk ^= (k&7)
#pragma unroll
  for (int r = 0; r < 4; ++r) {
    int p = tid * 4 + r * 1024;
    int i = p >> 6, k = p & 63;
    float4 v = *(const float4*)(trow + p);
    float vv[4] = {v.x, v.y, v.z, v.w};
#pragma unroll
    for (int q = 0; q < 4; ++q) {
      int row = k + q;
      int dst = row * 64 + ((((i >> 3) ^ (row & 7)) << 3)) + (i & 7);
      ushort h = f32_bf16(vv[q]);
      float hf = __uint_as_float((uint32_t)h << 16);
      Th[dst] = h;
      Tl[dst] = f32_bf16(vv[q] - hf);
    }
  }
  __syncthreads();

  const int w = tid >> 6, l = tid & 63;
  const int lrow = l & 15, kg = l >> 4;
  bf16x8 ah[2], al[2];
#pragma unroll
  for (int kt = 0; kt < 2; ++kt) {
    int off = (w * 16 + lrow) * 64 + kt * 32 + kg * 8;
    ah[kt] = *(const bf16x8*)(ch + off);
    al[kt] = *(const bf16x8*)(cl + off);
  }
#pragma unroll
  for (int jt = 0; jt < 4; ++jt) {
    f32x4 hh = (f32x4)0.0f, sm = (f32x4)0.0f;
#pragma unroll
    for (int kt = 0; kt < 2; ++kt) {
      int rowB = jt * 16 + lrow;
      int kcA  = kt * 4 + kg;
      int off  = rowB * 64 + ((kcA ^ (rowB & 7)) << 3);
      bf16x8 bh = *(const bf16x8*)&Th[off];
      bf16x8 bl = *(const bf16x8*)&Tl[off];
      hh = __builtin_amdgcn_mfma_f32_16x16x32_bf16(ah[kt], bh, hh, 0, 0, 0);
      sm = __builtin_amdgcn_mfma_f32_16x16x32_bf16(ah[kt], bl, sm, 0, 0, 0);
      sm = __builtin_amdgcn_mfma_f32_16x16x32_bf16(al[kt], bh, sm, 0, 0, 0);
      sm = __builtin_amdgcn_mfma_f32_16x16x32_bf16(al[kt], bl, sm, 0, 0, 0);  // ll
    }
#pragma unroll
    for (int q = 0; q < 4; ++q)
      trow[(w * 16 + kg * 4 + q) * 64 + jt * 16 + lrow] = hh[q] + sm[q];
  }
}

__global__ __launch_bounds__(256) void k_logp(const float* __restrict__ tail,
                                              const double* __restrict__ misc,
                                              float* __restrict__ out) {
  const int b = blockIdx.x * 256 + threadIdx.x;
  double tr = 0.0;
  for (int a = 0; a < 64; ++a) tr += (double)tail[(size_t)b * RR + a * 65];
  double lp = log(fmax(tr, 1e-30)) - misc[0];
  out[NDRAWS * KMODES + b] = (float)lp;
}

// ---------------- launcher ----------------
extern "C" void kernel_launch(void* const* d_in, const int* in_sizes, int n_in,
                              void* d_out, int out_size, void* d_ws, size_t ws_size,
                              hipStream_t stream) {
  (void)in_sizes; (void)n_in;
  CorePtrs cp;
  for (int i = 0; i < KMODES; ++i) cp.p[i] = (const float*)d_in[i];
  float* outf = (float*)d_out;

  char* base = (char*)d_ws;
  const size_t o_w     = 0;                                    // f32 W (step0) / float2 P
  const size_t o_tail  = o_w + (size_t)NDRAWS * D_CAT * 4;     // f32 2048*4096
  const size_t o_ahl   = o_tail + (size_t)NDRAWS * RR * 4;     // u16 Ah+Al (2x 2048*4096)
  const size_t o_spart = o_ahl;                                // f32 2048*4096 (prologue only)
  const size_t o_S     = o_ahl + (size_t)NDRAWS * RR * 4;      // f64 8*4096
  const size_t o_heads = o_S + (size_t)KMODES * RR * 8;        // f64 7*4096
  const size_t o_misc  = o_heads + (size_t)7 * RR * 8;         // f64 lognorm
  const size_t o_bh    = o_misc + 256;                         // u16 1024*4096
  const size_t o_bl    = o_bh + (size_t)D_CAT * RR * 2;        // u16 1024*4096
  const size_t NEED    = o_bl + (size_t)D_CAT * RR * 2;
  if (ws_size < NEED) {
    k_sentinel<<<(out_size + 255) / 256, 256, 0, stream>>>(outf, out_size);
    return;
  }

  float*  W     = (float*)(base + o_w);
  float2* P     = (float2*)(base + o_w);    // aliases W (disjoint step usage)
  float*  tail  = (float*)(base + o_tail);
  ushort* Ah    = (ushort*)(base + o_ahl);
  ushort* Al    = Ah + (size_t)NDRAWS * RR;
  float*  Spart = (float*)(base + o_spart);
  double* S     = (double*)(base + o_S);
  double* heads = (double*)(base + o_heads);
  double* misc  = (double*)(base + o_misc);
  ushort* Bh    = (ushort*)(base + o_bh);
  ushort* Bl    = (ushort*)(base + o_bl);

  // keys[s] = threefry2x32((0,1), (0,s))  -- split(key(1), 8), foldlike
  uint32_t kk1[KMODES], kk2[KMODES];
  for (uint32_t s = 0; s < KMODES; ++s) tf2x32(0u, 1u, 0u, s, kk1[s], kk2[s]);

  k_spart  <<<2048, 256, 0, stream>>>(cp, Spart);
  k_sreduce<<<128,  256, 0, stream>>>(Spart, S);
  k_heads  <<<1,    256, 0, stream>>>(S, heads, misc);

  for (int s = 0; s < KMODES; ++s) {
    const int j = 7 - s;
    if (s == 0) {
      k_w0<<<256, 256, 0, stream>>>(cp.p[7], heads + (size_t)6 * RR, W);
    } else {
      k_spmt<<<4608, 256, 0, stream>>>(cp.p[j], Bh, Bl, tail,
                                       j > 0 ? heads + (size_t)(j - 1) * RR : heads,
                                       j > 0 ? 1 : 0, Ah, Al);
      k_wgemm<<<512, 256, 0, stream>>>(Ah, Al, Bh, Bl, kk1[s], kk2[s], P);
    }
    k_samptail<<<NDRAWS, 256, 0, stream>>>(W, P, s == 0 ? 1 : 0, kk1[s], kk2[s],
                                           outf, j, cp.p[j], Bh, Bl, tail,
                                           s == 0 ? 1 : 0);
  }
  k_logp<<<KMODES, 256, 0, stream>>>(tail, misc, outf);
}

// Round 15
// 880.043 us; speedup vs baseline: 1.0346x; 1.0346x over previous
//
#include <hip/hip_runtime.h>
#include <stdint.h>
#include <math.h>

#define D_CAT  1024
#define R_TR   64
#define RR     4096      // R*R
#define NDRAWS 2048
#define KMODES 8

struct CorePtrs { const float* p[KMODES]; };

typedef __attribute__((ext_vector_type(8))) __bf16 bf16x8;
typedef __attribute__((ext_vector_type(4))) float  f32x4;
typedef unsigned int u32;

union BF8 { ushort u[8]; bf16x8 v; };

// async global->LDS 16B copy: LDS dest is wave-uniform base + lane*16
static __device__ inline void async_cp16(const void* g, void* l) {
  __builtin_amdgcn_global_load_lds(
      (const __attribute__((address_space(1))) u32*)g,
      (__attribute__((address_space(3))) u32*)l, 16, 0, 0);
}

// ---------------- threefry2x32 (JAX-exact, 20 rounds) ----------------
static __host__ __device__ inline uint32_t rotl32(uint32_t x, int r) {
  return (x << r) | (x >> (32 - r));
}
static __host__ __device__ inline void tf2x32(uint32_t k1, uint32_t k2,
                                              uint32_t x0, uint32_t x1,
                                              uint32_t& o0, uint32_t& o1) {
  uint32_t ks0 = k1, ks1 = k2, ks2 = k1 ^ k2 ^ 0x1BD11BDAu;
  x0 += ks0; x1 += ks1;
  x0 += x1; x1 = rotl32(x1, 13); x1 ^= x0;
  x0 += x1; x1 = rotl32(x1, 15); x1 ^= x0;
  x0 += x1; x1 = rotl32(x1, 26); x1 ^= x0;
  x0 += x1; x1 = rotl32(x1, 6);  x1 ^= x0;
  x0 += ks1; x1 += ks2 + 1u;
  x0 += x1; x1 = rotl32(x1, 17); x1 ^= x0;
  x0 += x1; x1 = rotl32(x1, 29); x1 ^= x0;
  x0 += x1; x1 = rotl32(x1, 16); x1 ^= x0;
  x0 += x1; x1 = rotl32(x1, 24); x1 ^= x0;
  x0 += ks2; x1 += ks0 + 2u;
  x0 += x1; x1 = rotl32(x1, 13); x1 ^= x0;
  x0 += x1; x1 = rotl32(x1, 15); x1 ^= x0;
  x0 += x1; x1 = rotl32(x1, 26); x1 ^= x0;
  x0 += x1; x1 = rotl32(x1, 6);  x1 ^= x0;
  x0 += ks0; x1 += ks1 + 3u;
  x0 += x1; x1 = rotl32(x1, 17); x1 ^= x0;
  x0 += x1; x1 = rotl32(x1, 29); x1 ^= x0;
  x0 += x1; x1 = rotl32(x1, 16); x1 ^= x0;
  x0 += x1; x1 = rotl32(x1, 24); x1 ^= x0;
  x0 += ks1; x1 += ks2 + 4u;
  x0 += x1; x1 = rotl32(x1, 13); x1 ^= x0;
  x0 += x1; x1 = rotl32(x1, 15); x1 ^= x0;
  x0 += x1; x1 = rotl32(x1, 26); x1 ^= x0;
  x0 += x1; x1 = rotl32(x1, 6);  x1 ^= x0;
  x0 += ks2; x1 += ks0 + 5u;
  o0 = x0; o1 = x1;
}

// fast softplus: max(x,0)+log(1+exp(-|x|)) via v_exp_f32/v_log_f32.
static __device__ inline float softplus_fast(float x) {
  float e = __expf(-fabsf(x));
  return fmaxf(x, 0.0f) + __logf(1.0f + e);
}

static __device__ inline unsigned short f32_bf16(float f) {  // RNE
  uint32_t u = __float_as_uint(f);
  u += 0x7fffu + ((u >> 16) & 1u);
  return (unsigned short)(u >> 16);
}

// gumbel for flat element e under key (k1,k2), partitionable path
static __device__ inline float gumbel_at(uint32_t k1, uint32_t k2, uint32_t e) {
  uint32_t o0, o1;
  tf2x32(k1, k2, 0u, e, o0, o1);
  uint32_t bits = o0 ^ o1;
  float f = __uint_as_float((bits >> 9) | 0x3F800000u) - 1.0f;
  float u = (f > 0.0f) ? f : 1.17549435e-38f;   // finfo(f32).tiny
  return -logf(-logf(u));
}

// ---------------- kernels ----------------

__global__ void k_sentinel(float* out, int n) {
  int i = blockIdx.x * 256 + threadIdx.x;
  if (i < n) out[i] = -12288.0f;  // ws-too-small marker
}

// partial column sums of softplus(core_i): grid 8*256 (4 d-rows each)
__global__ __launch_bounds__(256) void k_spart(CorePtrs cp, float* __restrict__ Spart) {
  const int bid = blockIdx.x, tid = threadIdx.x;
  const int i = bid >> 8, c = bid & 255;
  const float* src = cp.p[i] + (size_t)c * 4 * RR;
  float acc[16];
#pragma unroll
  for (int k = 0; k < 16; ++k) acc[k] = 0.0f;
#pragma unroll
  for (int d = 0; d < 4; ++d) {
    const float* row = src + (size_t)d * RR;
#pragma unroll
    for (int k = 0; k < 16; ++k)
      acc[k] += softplus_fast(row[tid + k * 256]);
  }
  float* dst = Spart + (size_t)bid * RR;
#pragma unroll
  for (int k = 0; k < 16; ++k) dst[tid + k * 256] = acc[k];
}

// reduce 256 f32 partials -> S[i][rr] f64: grid 128, block 256
__global__ __launch_bounds__(256) void k_sreduce(const float* __restrict__ Spart,
                                                 double* __restrict__ S) {
  const int idx = blockIdx.x * 256 + threadIdx.x;   // 0..32767
  const int i = idx >> 12, rr = idx & 4095;
  const float* p = Spart + ((size_t)i << 20) + rr;  // i*256*4096
  double a0 = 0.0, a1 = 0.0, a2 = 0.0, a3 = 0.0;
  for (int c = 0; c < 256; c += 4) {
    a0 += (double)p[(size_t)(c + 0) * RR];
    a1 += (double)p[(size_t)(c + 1) * RR];
    a2 += (double)p[(size_t)(c + 2) * RR];
    a3 += (double)p[(size_t)(c + 3) * RR];
  }
  S[idx] = (a0 + a1) + (a2 + a3);
}

// heads chain + log(trace(norm)): 1 block, 256 threads.
__global__ __launch_bounds__(256) void k_heads(const double* __restrict__ S,
                                               double* __restrict__ heads,
                                               double* __restrict__ misc) {
  __shared__ double cur[RR];
  __shared__ double Sm[RR];
  __shared__ double tbuf[64];
  const int tid = threadIdx.x;
  const int bcol = tid & 63;
  const int a0 = tid >> 6;
#pragma unroll
  for (int k = 0; k < 16; ++k) {
    int p = tid + k * 256;
    double v = S[p];
    cur[p] = v;
    heads[p] = v;          // slot 0 = heads[1] = S0
  }
  __syncthreads();
  for (int m = 1; m <= 6; ++m) {
#pragma unroll
    for (int k = 0; k < 16; ++k) {
      int p = tid + k * 256;
      Sm[p] = S[(size_t)m * RR + p];
    }
    __syncthreads();
    double acc[16];
#pragma unroll
    for (int k = 0; k < 16; ++k) acc[k] = 0.0;
    for (int c = 0; c < 64; ++c) {
      double s = Sm[c * 64 + bcol];
#pragma unroll
      for (int k = 0; k < 16; ++k)
        acc[k] = fma(cur[(a0 + 4 * k) * 64 + c], s, acc[k]);
    }
    __syncthreads();
#pragma unroll
    for (int k = 0; k < 16; ++k) {
      int p = tid + k * 256;     // == (a0+4k)*64 + bcol
      cur[p] = acc[k];
      heads[(size_t)m * RR + p] = acc[k];
    }
    __syncthreads();
  }
  // trace(norm) = trace(cur @ S7), S7 staged in LDS
#pragma unroll
  for (int k = 0; k < 16; ++k) {
    int p = tid + k * 256;
    Sm[p] = S[(size_t)7 * RR + p];
  }
  __syncthreads();
  if (tid < 64) {
    double acc = 0.0;
    for (int c = 0; c < 64; ++c)
      acc = fma(cur[tid * 64 + c], Sm[c * 64 + tid], acc);
    tbuf[tid] = acc;
  }
  __syncthreads();
  if (tid == 0) {
    double tr = 0.0;
    for (int a = 0; a < 64; ++a) tr += tbuf[a];
    misc[0] = log(tr);
  }
}

// step 0 weights from RAW core (inline softplus)
__global__ __launch_bounds__(256) void k_w0(const float* __restrict__ raw,
                                            const double* __restrict__ head7,
                                            float* __restrict__ W) {
  const int tid = threadIdx.x;
  const int lane = tid & 63;
  const int n = blockIdx.x * 4 + (tid >> 6);
  const float* crow = raw + (size_t)n * RR;
  double acc = 0.0;
  for (int q = lane; q < RR; q += 64)
    acc = fma((double)softplus_fast(crow[q]), head7[(q & 63) * 64 + (q >> 6)], acc);
  for (int m = 32; m; m >>= 1) acc += __shfl_xor(acc, m);
  if (lane == 0) W[n] = (float)acc;
}

// FUSED: blocks 0..4095 = softplus(core_j)->Bh/Bl split;
//        blocks 4096..4607 = Mt build (MFMA w/ head, or direct transpose if !useHead)
__global__ __launch_bounds__(256) void k_spmt(const float* __restrict__ src,
                                              ushort* __restrict__ Bh,
                                              ushort* __restrict__ Bl,
                                              const float* __restrict__ tail,
                                              const double* __restrict__ head, int useHead,
                                              ushort* __restrict__ Ah,
                                              ushort* __restrict__ Al) {
  __shared__ alignas(16) float smem[4176];   // 16.7KB: mt2 hT(16KB) or mtid 64x65 f32
  const int bid = blockIdx.x, tid = threadIdx.x;
  if (bid < 4096) {
    // ---- softplus split path ----
    const size_t i4 = ((size_t)bid * 256 + tid) * 4;
    float4 v = *(const float4*)(src + i4);
    const float ov[4] = {softplus_fast(v.x), softplus_fast(v.y),
                         softplus_fast(v.z), softplus_fast(v.w)};
    ushort h4[4], l4[4];
#pragma unroll
    for (int q = 0; q < 4; ++q) {
      ushort h = f32_bf16(ov[q]);
      float hf = __uint_as_float((uint32_t)h << 16);
      h4[q] = h;
      l4[q] = f32_bf16(ov[q] - hf);
    }
    *(ushort4*)(Bh + i4) = make_ushort4(h4[0], h4[1], h4[2], h4[3]);
    *(ushort4*)(Bl + i4) = make_ushort4(l4[0], l4[1], l4[2], l4[3]);
    return;
  }
  const int blk = bid - 4096;   // 0..511
  if (useHead) {
    // ---- mt2: Mt[B,k*64+i] = sum_c tail[B,i,c]*head[c,k] via bf16 3-pass ----
    ushort (*hT)[4096] = (ushort(*)[4096])smem;
#pragma unroll
    for (int rep = 0; rep < 16; ++rep) {
      int i = tid + rep * 256;
      float v = (float)head[(i & 63) * 64 + (i >> 6)];
      ushort h = f32_bf16(v);
      float hf = __uint_as_float((uint32_t)h << 16);
      int dst = (i & 0xFC0) | (((((i >> 3) & 7) ^ ((i >> 6) & 7)) << 3)) | (i & 7);
      hT[0][dst] = h;
      hT[1][dst] = f32_bf16(v - hf);
    }
    __syncthreads();
    const int w = tid >> 6, l = tid & 63;
    const int B = blk * 4 + w;
    const float* tb = tail + (size_t)B * RR;
    const int lrow = l & 15, kg = l >> 4;
    ushort* ah_out = Ah + (size_t)B * RR;
    ushort* al_out = Al + (size_t)B * RR;
    for (int it = 0; it < 4; ++it) {
      BF8 afh[2], afl[2];
#pragma unroll
      for (int kt = 0; kt < 2; ++kt) {
        const float* s2 = tb + (it * 16 + lrow) * 64 + kt * 32 + kg * 8;
        float4 v0 = *(const float4*)s2;
        float4 v1 = *(const float4*)(s2 + 4);
        float vv[8] = {v0.x, v0.y, v0.z, v0.w, v1.x, v1.y, v1.z, v1.w};
#pragma unroll
        for (int q = 0; q < 8; ++q) {
          ushort h = f32_bf16(vv[q]);
          float hf = __uint_as_float((uint32_t)h << 16);
          afh[kt].u[q] = h;
          afl[kt].u[q] = f32_bf16(vv[q] - hf);
        }
      }
#pragma unroll
      for (int kt2 = 0; kt2 < 4; ++kt2) {
        f32x4 hh = (f32x4)0.0f, sm = (f32x4)0.0f;
#pragma unroll
        for (int kt = 0; kt < 2; ++kt) {
          int rowB = kt2 * 16 + lrow;
          int kcA  = kt * 4 + kg;
          int off  = rowB * 64 + ((kcA ^ (rowB & 7)) << 3);
          bf16x8 bh = *(const bf16x8*)&hT[0][off];
          bf16x8 bl = *(const bf16x8*)&hT[1][off];
          hh = __builtin_amdgcn_mfma_f32_16x16x32_bf16(afh[kt].v, bh, hh, 0, 0, 0);
          sm = __builtin_amdgcn_mfma_f32_16x16x32_bf16(afh[kt].v, bl, sm, 0, 0, 0);
          sm = __builtin_amdgcn_mfma_f32_16x16x32_bf16(afl[kt].v, bh, sm, 0, 0, 0);
        }
        ushort h4[4], l4[4];
#pragma unroll
        for (int q = 0; q < 4; ++q) {
          float v = hh[q] + sm[q];
          ushort h = f32_bf16(v);
          float hf = __uint_as_float((uint32_t)h << 16);
          h4[q] = h;
          l4[q] = f32_bf16(v - hf);
        }
        int o = (kt2 * 16 + lrow) * 64 + it * 16 + kg * 4;   // Mt = k*64 + i
        *(ushort4*)(ah_out + o) = make_ushort4(h4[0], h4[1], h4[2], h4[3]);
        *(ushort4*)(al_out + o) = make_ushort4(l4[0], l4[1], l4[2], l4[3]);
      }
    }
  } else {
    // ---- mtid: Mt[B,k*64+i] = tail[B,i,k] (head==I), pure transpose+split ----
    float* tl = smem;   // [64][65] padded
    for (int d = 0; d < 4; ++d) {
      const int B = blk * 4 + d;
      const float* tb = tail + (size_t)B * RR;
      ushort* ah_out = Ah + (size_t)B * RR;
      ushort* al_out = Al + (size_t)B * RR;
      __syncthreads();
#pragma unroll
      for (int r = 0; r < 4; ++r) {
        int p = tid * 4 + r * 1024;
        int i = p >> 6, k = p & 63;
        float4 v = *(const float4*)(tb + p);
        tl[i * 65 + k + 0] = v.x; tl[i * 65 + k + 1] = v.y;
        tl[i * 65 + k + 2] = v.z; tl[i * 65 + k + 3] = v.w;
      }
      __syncthreads();
#pragma unroll
      for (int r = 0; r < 4; ++r) {
        int p = tid * 4 + r * 1024;
        int k = p >> 6, i0 = p & 63;
        ushort h4[4], l4[4];
#pragma unroll
        for (int q = 0; q < 4; ++q) {
          float m = tl[(i0 + q) * 65 + k];
          ushort h = f32_bf16(m);
          float hf = __uint_as_float((uint32_t)h << 16);
          h4[q] = h;
          l4[q] = f32_bf16(m - hf);
        }
        *(ushort4*)(ah_out + p) = make_ushort4(h4[0], h4[1], h4[2], h4[3]);
        *(ushort4*)(al_out + p) = make_ushort4(l4[0], l4[1], l4[2], l4[3]);
      }
    }
  }
}

// Split-K x2 W-GEMM: grid 1024 = 2 halves x 512-block XCD-swizzled tiles.
// Each half computes K=2048 and writes Wp[half]; samptail sums the halves.
// Single 32KB LDS buffer -> 4 blocks/CU co-resident (inter-block overlap
// replaces intra-block double-buffering).
__global__ __launch_bounds__(256) void k_wgemm(const ushort* __restrict__ Ah,
                                               const ushort* __restrict__ Al,
                                               const ushort* __restrict__ Bh,
                                               const ushort* __restrict__ Bl,
                                               float* __restrict__ W) {
  __shared__ ushort lds[4 * 4096];     // 32KB, single buffer
  const int tid = threadIdx.x;
  const int L = blockIdx.x;            // 0..1023
  const int half = L >> 9;             // K half
  const int r = L & 511;
  const int x = r & 7, j = r >> 3;
  const int bn = (x & 1) * 8 + (j & 7);
  const int bb = (x >> 1) * 8 + (j >> 3);
  const int w = tid >> 6, l = tid & 63;

  const int srow = l >> 3;
  const int skc  = l & 7;
  const ushort* gbase;
  {
    const ushort* bases[4] = {Ah + (size_t)bb * 64 * RR, Al + (size_t)bb * 64 * RR,
                              Bh + (size_t)bn * 64 * RR, Bl + (size_t)bn * 64 * RR};
    gbase = bases[w] + (size_t)srow * RR + (size_t)((skc ^ srow) * 8)
          + (size_t)half * 2048;       // K-half offset
  }

  const int wm = (w >> 1) * 32, wn = (w & 1) * 32;
  const int lrow = l & 15;
  const int kg   = l >> 4;

  f32x4 acc_hh[2][2], acc_sm[2][2], hht[2][2];
#pragma unroll
  for (int mt = 0; mt < 2; ++mt)
#pragma unroll
    for (int nt = 0; nt < 2; ++nt) {
      acc_hh[mt][nt] = (f32x4)0.0f;
      acc_sm[mt][nt] = (f32x4)0.0f;
      hht[mt][nt]    = (f32x4)0.0f;
    }

  int roffA[2][2], roffB[2][2];
#pragma unroll
  for (int mt = 0; mt < 2; ++mt)
#pragma unroll
    for (int kt = 0; kt < 2; ++kt) {
      int rowA = wm + mt * 16 + lrow;
      int kcA  = kt * 4 + kg;
      roffA[mt][kt] = rowA * 64 + ((kcA ^ (rowA & 7)) << 3);
      int rowB = wn + mt * 16 + lrow;
      roffB[mt][kt] = rowB * 64 + ((kcA ^ (rowB & 7)) << 3);
    }

  for (int t = 0; t < 32; ++t) {
    __syncthreads();   // all waves done reading previous tile
#pragma unroll
    for (int q = 0; q < 8; ++q)
      async_cp16(gbase + (size_t)q * 8 * RR + t * 64, &lds[w * 4096 + q * 512]);
    __syncthreads();   // drains vmcnt: tile landed
#pragma unroll
    for (int kt = 0; kt < 2; ++kt) {
      bf16x8 ah[2], al[2], bh[2], bl[2];
#pragma unroll
      for (int mt = 0; mt < 2; ++mt) {
        ah[mt] = *(const bf16x8*)&lds[0 * 4096 + roffA[mt][kt]];
        al[mt] = *(const bf16x8*)&lds[1 * 4096 + roffA[mt][kt]];
      }
#pragma unroll
      for (int nt = 0; nt < 2; ++nt) {
        bh[nt] = *(const bf16x8*)&lds[2 * 4096 + roffB[nt][kt]];
        bl[nt] = *(const bf16x8*)&lds[3 * 4096 + roffB[nt][kt]];
      }
#pragma unroll
      for (int mt = 0; mt < 2; ++mt)
#pragma unroll
        for (int nt = 0; nt < 2; ++nt) {
          acc_hh[mt][nt] = __builtin_amdgcn_mfma_f32_16x16x32_bf16(ah[mt], bh[nt], acc_hh[mt][nt], 0, 0, 0);
          acc_sm[mt][nt] = __builtin_amdgcn_mfma_f32_16x16x32_bf16(ah[mt], bl[nt], acc_sm[mt][nt], 0, 0, 0);
          acc_sm[mt][nt] = __builtin_amdgcn_mfma_f32_16x16x32_bf16(al[mt], bh[nt], acc_sm[mt][nt], 0, 0, 0);
        }
    }
    if ((t & 15) == 15) {   // chunk dump every 1024 k (same boundaries as before)
#pragma unroll
      for (int mt = 0; mt < 2; ++mt)
#pragma unroll
        for (int nt = 0; nt < 2; ++nt) {
          hht[mt][nt] += acc_hh[mt][nt];
          acc_hh[mt][nt] = (f32x4)0.0f;
        }
    }
  }

  float* Wout = W + (size_t)half * NDRAWS * D_CAT;
#pragma unroll
  for (int mt = 0; mt < 2; ++mt)
#pragma unroll
    for (int nt = 0; nt < 2; ++nt)
#pragma unroll
      for (int q = 0; q < 4; ++q) {
        int gr = bb * 64 + wm + mt * 16 + kg * 4 + q;
        int gc = bn * 64 + wn + nt * 16 + lrow;
        Wout[(size_t)gr * D_CAT + gc] = hht[mt][nt][q] + acc_sm[mt][nt][q];
      }
}

// FUSED sample + tail-update: one block per draw.
// Phase 1: gumbel-argmax; w = W row (shared, step0) or Wp0+Wp1 per-draw rows.
// Phase 2: tail[b] = C[m] @ tail[b] via MFMA 4-pass (or softplus-copy if first).
__global__ __launch_bounds__(256) void k_samptail(const float* __restrict__ W, int shared_row,
                                                  uint32_t key1, uint32_t key2,
                                                  float* __restrict__ out, int mode_j,
                                                  const float* __restrict__ raw,
                                                  const ushort* __restrict__ Bh,
                                                  const ushort* __restrict__ Bl,
                                                  float* __restrict__ tail, int first) {
  __shared__ float sv[4];
  __shared__ int   si[4];
  __shared__ int   s_m;
  __shared__ alignas(16) ushort Th[4096];
  __shared__ alignas(16) ushort Tl[4096];
  const int b = blockIdx.x, tid = threadIdx.x;

  // ---- phase 1: argmax(gumbel + log w) ----
  {
    const float* w0row = W + (shared_row ? 0 : (size_t)b * D_CAT);
    const float* w1row = W + (size_t)NDRAWS * D_CAT + (size_t)b * D_CAT;
    float best = -3.4e38f; int bidx = 0x7fffffff;
    for (int k = 0; k < 4; ++k) {
      int n = tid + k * 256;
      float wv = shared_row ? w0row[n] : (w0row[n] + w1row[n]);
      float lg = logf(fmaxf(wv, 1e-30f));
      float v = gumbel_at(key1, key2, (uint32_t)(b * D_CAT + n)) + lg;
      if (v > best || (v == best && n < bidx)) { best = v; bidx = n; }
    }
    for (int m = 32; m; m >>= 1) {
      float ov = __shfl_xor(best, m);
      int   oi = __shfl_xor(bidx, m);
      if (ov > best || (ov == best && oi < bidx)) { best = ov; bidx = oi; }
    }
    if ((tid & 63) == 0) { sv[tid >> 6] = best; si[tid >> 6] = bidx; }
    __syncthreads();
    if (tid == 0) {
      for (int t = 1; t < 4; ++t)
        if (sv[t] > best || (sv[t] == best && si[t] < bidx)) { best = sv[t]; bidx = si[t]; }
      s_m = bidx;
      out[b * KMODES + mode_j] = (float)bidx;
    }
    __syncthreads();
  }
  const int m = s_m;
  float* trow = tail + (size_t)b * RR;

  // ---- phase 2: tail update ----
  if (first) {
    const float* crow = raw + (size_t)m * RR;
#pragma unroll
    for (int r = 0; r < 4; ++r) {
      float4 v = *(const float4*)(crow + tid * 4 + r * 1024);
      float4 o;
      o.x = softplus_fast(v.x); o.y = softplus_fast(v.y);
      o.z = softplus_fast(v.z); o.w = softplus_fast(v.w);
      *(float4*)(trow + tid * 4 + r * 1024) = o;
    }
    return;
  }
  const ushort* ch = Bh + (size_t)m * RR;
  const ushort* cl = Bl + (size_t)m * RR;

  // transpose+split old tail into Th/Tl [k][c], chunk ^= (k&7)
#pragma unroll
  for (int r = 0; r < 4; ++r) {
    int p = tid * 4 + r * 1024;
    int i = p >> 6, k = p & 63;
    float4 v = *(const float4*)(trow + p);
    float vv[4] = {v.x, v.y, v.z, v.w};
#pragma unroll
    for (int q = 0; q < 4; ++q) {
      int row = k + q;
      int dst = row * 64 + ((((i >> 3) ^ (row & 7)) << 3)) + (i & 7);
      ushort h = f32_bf16(vv[q]);
      float hf = __uint_as_float((uint32_t)h << 16);
      Th[dst] = h;
      Tl[dst] = f32_bf16(vv[q] - hf);
    }
  }
  __syncthreads();

  const int w = tid >> 6, l = tid & 63;
  const int lrow = l & 15, kg = l >> 4;
  bf16x8 ah[2], al[2];
#pragma unroll
  for (int kt = 0; kt < 2; ++kt) {
    int off = (w * 16 + lrow) * 64 + kt * 32 + kg * 8;
    ah[kt] = *(const bf16x8*)(ch + off);
    al[kt] = *(const bf16x8*)(cl + off);
  }
#pragma unroll
  for (int jt = 0; jt < 4; ++jt) {
    f32x4 hh = (f32x4)0.0f, sm = (f32x4)0.0f;
#pragma unroll
    for (int kt = 0; kt < 2; ++kt) {
      int rowB = jt * 16 + lrow;
      int kcA  = kt * 4 + kg;
      int off  = rowB * 64 + ((kcA ^ (rowB & 7)) << 3);
      bf16x8 bh = *(const bf16x8*)&Th[off];
      bf16x8 bl = *(const bf16x8*)&Tl[off];
      hh = __builtin_amdgcn_mfma_f32_16x16x32_bf16(ah[kt], bh, hh, 0, 0, 0);
      sm = __builtin_amdgcn_mfma_f32_16x16x32_bf16(ah[kt], bl, sm, 0, 0, 0);
      sm = __builtin_amdgcn_mfma_f32_16x16x32_bf16(al[kt], bh, sm, 0, 0, 0);
      sm = __builtin_amdgcn_mfma_f32_16x16x32_bf16(al[kt], bl, sm, 0, 0, 0);  // ll
    }
#pragma unroll
    for (int q = 0; q < 4; ++q)
      trow[(w * 16 + kg * 4 + q) * 64 + jt * 16 + lrow] = hh[q] + sm[q];
  }
}

__global__ __launch_bounds__(256) void k_logp(const float* __restrict__ tail,
                                              const double* __restrict__ misc,
                                              float* __restrict__ out) {
  const int b = blockIdx.x * 256 + threadIdx.x;
  double tr = 0.0;
  for (int a = 0; a < 64; ++a) tr += (double)tail[(size_t)b * RR + a * 65];
  double lp = log(fmax(tr, 1e-30)) - misc[0];
  out[NDRAWS * KMODES + b] = (float)lp;
}

// ---------------- launcher ----------------
extern "C" void kernel_launch(void* const* d_in, const int* in_sizes, int n_in,
                              void* d_out, int out_size, void* d_ws, size_t ws_size,
                              hipStream_t stream) {
  (void)in_sizes; (void)n_in;
  CorePtrs cp;
  for (int i = 0; i < KMODES; ++i) cp.p[i] = (const float*)d_in[i];
  float* outf = (float*)d_out;

  char* base = (char*)d_ws;
  const size_t o_w     = 0;                                    // f32 2x 2048*1024 (split-K halves)
  const size_t o_tail  = o_w + (size_t)2 * NDRAWS * D_CAT * 4; // f32 2048*4096
  const size_t o_ahl   = o_tail + (size_t)NDRAWS * RR * 4;     // u16 Ah+Al (2x 2048*4096)
  const size_t o_spart = o_ahl;                                // f32 2048*4096 (prologue only)
  const size_t o_S     = o_ahl + (size_t)NDRAWS * RR * 4;      // f64 8*4096
  const size_t o_heads = o_S + (size_t)KMODES * RR * 8;        // f64 7*4096
  const size_t o_misc  = o_heads + (size_t)7 * RR * 8;         // f64 lognorm
  const size_t o_bh    = o_misc + 256;                         // u16 1024*4096
  const size_t o_bl    = o_bh + (size_t)D_CAT * RR * 2;        // u16 1024*4096
  const size_t NEED    = o_bl + (size_t)D_CAT * RR * 2;
  if (ws_size < NEED) {
    k_sentinel<<<(out_size + 255) / 256, 256, 0, stream>>>(outf, out_size);
    return;
  }

  float*  W     = (float*)(base + o_w);
  float*  tail  = (float*)(base + o_tail);
  ushort* Ah    = (ushort*)(base + o_ahl);
  ushort* Al    = Ah + (size_t)NDRAWS * RR;
  float*  Spart = (float*)(base + o_spart);
  double* S     = (double*)(base + o_S);
  double* heads = (double*)(base + o_heads);
  double* misc  = (double*)(base + o_misc);
  ushort* Bh    = (ushort*)(base + o_bh);
  ushort* Bl    = (ushort*)(base + o_bl);

  // keys[s] = threefry2x32((0,1), (0,s))  -- split(key(1), 8), foldlike
  uint32_t kk1[KMODES], kk2[KMODES];
  for (uint32_t s = 0; s < KMODES; ++s) tf2x32(0u, 1u, 0u, s, kk1[s], kk2[s]);

  k_spart  <<<2048, 256, 0, stream>>>(cp, Spart);
  k_sreduce<<<128,  256, 0, stream>>>(Spart, S);
  k_heads  <<<1,    256, 0, stream>>>(S, heads, misc);

  for (int s = 0; s < KMODES; ++s) {
    const int j = 7 - s;
    if (s == 0) {
      k_w0<<<256, 256, 0, stream>>>(cp.p[7], heads + (size_t)6 * RR, W);
    } else {
      k_spmt<<<4608, 256, 0, stream>>>(cp.p[j], Bh, Bl, tail,
                                       j > 0 ? heads + (size_t)(j - 1) * RR : heads,
                                       j > 0 ? 1 : 0, Ah, Al);
      k_wgemm<<<1024, 256, 0, stream>>>(Ah, Al, Bh, Bl, W);
    }
    k_samptail<<<NDRAWS, 256, 0, stream>>>(W, s == 0 ? 1 : 0, kk1[s], kk2[s],
                                           outf, j, cp.p[j], Bh, Bl, tail,
                                           s == 0 ? 1 : 0);
  }
  k_logp<<<KMODES, 256, 0, stream>>>(tail, misc, outf);
}

// Round 17
// 838.983 us; speedup vs baseline: 1.0852x; 1.0489x over previous
//
#include <hip/hip_runtime.h>
#include <stdint.h>
#include <math.h>

#define D_CAT  1024
#define R_TR   64
#define RR     4096      // R*R
#define NDRAWS 2048
#define KMODES 8

struct CorePtrs { const float* p[KMODES]; };

typedef __attribute__((ext_vector_type(8))) __bf16 bf16x8;
typedef __attribute__((ext_vector_type(4))) float  f32x4;
typedef unsigned int u32;

union BF8 { ushort u[8]; bf16x8 v; };

// async global->LDS 16B copy: LDS dest is wave-uniform base + lane*16
static __device__ inline void async_cp16(const void* g, void* l) {
  __builtin_amdgcn_global_load_lds(
      (const __attribute__((address_space(1))) u32*)g,
      (__attribute__((address_space(3))) u32*)l, 16, 0, 0);
}

// ---------------- threefry2x32 (JAX-exact, 20 rounds) ----------------
static __host__ __device__ inline uint32_t rotl32(uint32_t x, int r) {
  return (x << r) | (x >> (32 - r));
}
static __host__ __device__ inline void tf2x32(uint32_t k1, uint32_t k2,
                                              uint32_t x0, uint32_t x1,
                                              uint32_t& o0, uint32_t& o1) {
  uint32_t ks0 = k1, ks1 = k2, ks2 = k1 ^ k2 ^ 0x1BD11BDAu;
  x0 += ks0; x1 += ks1;
  x0 += x1; x1 = rotl32(x1, 13); x1 ^= x0;
  x0 += x1; x1 = rotl32(x1, 15); x1 ^= x0;
  x0 += x1; x1 = rotl32(x1, 26); x1 ^= x0;
  x0 += x1; x1 = rotl32(x1, 6);  x1 ^= x0;
  x0 += ks1; x1 += ks2 + 1u;
  x0 += x1; x1 = rotl32(x1, 17); x1 ^= x0;
  x0 += x1; x1 = rotl32(x1, 29); x1 ^= x0;
  x0 += x1; x1 = rotl32(x1, 16); x1 ^= x0;
  x0 += x1; x1 = rotl32(x1, 24); x1 ^= x0;
  x0 += ks2; x1 += ks0 + 2u;
  x0 += x1; x1 = rotl32(x1, 13); x1 ^= x0;
  x0 += x1; x1 = rotl32(x1, 15); x1 ^= x0;
  x0 += x1; x1 = rotl32(x1, 26); x1 ^= x0;
  x0 += x1; x1 = rotl32(x1, 6);  x1 ^= x0;
  x0 += ks0; x1 += ks1 + 3u;
  x0 += x1; x1 = rotl32(x1, 17); x1 ^= x0;
  x0 += x1; x1 = rotl32(x1, 29); x1 ^= x0;
  x0 += x1; x1 = rotl32(x1, 16); x1 ^= x0;
  x0 += x1; x1 = rotl32(x1, 24); x1 ^= x0;
  x0 += ks1; x1 += ks2 + 4u;
  x0 += x1; x1 = rotl32(x1, 13); x1 ^= x0;
  x0 += x1; x1 = rotl32(x1, 15); x1 ^= x0;
  x0 += x1; x1 = rotl32(x1, 26); x1 ^= x0;
  x0 += x1; x1 = rotl32(x1, 6);  x1 ^= x0;
  x0 += ks2; x1 += ks0 + 5u;
  o0 = x0; o1 = x1;
}

// fast softplus: max(x,0)+log(1+exp(-|x|)) via v_exp_f32/v_log_f32.
static __device__ inline float softplus_fast(float x) {
  float e = __expf(-fabsf(x));
  return fmaxf(x, 0.0f) + __logf(1.0f + e);
}

static __device__ inline unsigned short f32_bf16(float f) {  // RNE
  uint32_t u = __float_as_uint(f);
  u += 0x7fffu + ((u >> 16) & 1u);
  return (unsigned short)(u >> 16);
}

// gumbel for flat element e under key (k1,k2), partitionable path
static __device__ inline float gumbel_at(uint32_t k1, uint32_t k2, uint32_t e) {
  uint32_t o0, o1;
  tf2x32(k1, k2, 0u, e, o0, o1);
  uint32_t bits = o0 ^ o1;
  float f = __uint_as_float((bits >> 9) | 0x3F800000u) - 1.0f;
  float u = (f > 0.0f) ? f : 1.17549435e-38f;   // finfo(f32).tiny
  return -logf(-logf(u));
}

// ---------------- kernels ----------------

__global__ void k_sentinel(float* out, int n) {
  int i = blockIdx.x * 256 + threadIdx.x;
  if (i < n) out[i] = -12288.0f;  // ws-too-small marker
}

// partial column sums of softplus(core_i): grid 8*256 (4 d-rows each)
__global__ __launch_bounds__(256) void k_spart(CorePtrs cp, float* __restrict__ Spart) {
  const int bid = blockIdx.x, tid = threadIdx.x;
  const int i = bid >> 8, c = bid & 255;
  const float* src = cp.p[i] + (size_t)c * 4 * RR;
  float acc[16];
#pragma unroll
  for (int k = 0; k < 16; ++k) acc[k] = 0.0f;
#pragma unroll
  for (int d = 0; d < 4; ++d) {
    const float* row = src + (size_t)d * RR;
#pragma unroll
    for (int k = 0; k < 16; ++k)
      acc[k] += softplus_fast(row[tid + k * 256]);
  }
  float* dst = Spart + (size_t)bid * RR;
#pragma unroll
  for (int k = 0; k < 16; ++k) dst[tid + k * 256] = acc[k];
}

// reduce 256 f32 partials -> S[i][rr] f64: grid 128, block 256
__global__ __launch_bounds__(256) void k_sreduce(const float* __restrict__ Spart,
                                                 double* __restrict__ S) {
  const int idx = blockIdx.x * 256 + threadIdx.x;   // 0..32767
  const int i = idx >> 12, rr = idx & 4095;
  const float* p = Spart + ((size_t)i << 20) + rr;  // i*256*4096
  double a0 = 0.0, a1 = 0.0, a2 = 0.0, a3 = 0.0;
  for (int c = 0; c < 256; c += 4) {
    a0 += (double)p[(size_t)(c + 0) * RR];
    a1 += (double)p[(size_t)(c + 1) * RR];
    a2 += (double)p[(size_t)(c + 2) * RR];
    a3 += (double)p[(size_t)(c + 3) * RR];
  }
  S[idx] = (a0 + a1) + (a2 + a3);
}

// heads chain + log(trace(norm)): 1 block, 256 threads.
__global__ __launch_bounds__(256) void k_heads(const double* __restrict__ S,
                                               double* __restrict__ heads,
                                               double* __restrict__ misc) {
  __shared__ double cur[RR];
  __shared__ double Sm[RR];
  __shared__ double tbuf[64];
  const int tid = threadIdx.x;
  const int bcol = tid & 63;
  const int a0 = tid >> 6;
#pragma unroll
  for (int k = 0; k < 16; ++k) {
    int p = tid + k * 256;
    double v = S[p];
    cur[p] = v;
    heads[p] = v;          // slot 0 = heads[1] = S0
  }
  __syncthreads();
  for (int m = 1; m <= 6; ++m) {
#pragma unroll
    for (int k = 0; k < 16; ++k) {
      int p = tid + k * 256;
      Sm[p] = S[(size_t)m * RR + p];
    }
    __syncthreads();
    double acc[16];
#pragma unroll
    for (int k = 0; k < 16; ++k) acc[k] = 0.0;
    for (int c = 0; c < 64; ++c) {
      double s = Sm[c * 64 + bcol];
#pragma unroll
      for (int k = 0; k < 16; ++k)
        acc[k] = fma(cur[(a0 + 4 * k) * 64 + c], s, acc[k]);
    }
    __syncthreads();
#pragma unroll
    for (int k = 0; k < 16; ++k) {
      int p = tid + k * 256;     // == (a0+4k)*64 + bcol
      cur[p] = acc[k];
      heads[(size_t)m * RR + p] = acc[k];
    }
    __syncthreads();
  }
  // trace(norm) = trace(cur @ S7), S7 staged in LDS
#pragma unroll
  for (int k = 0; k < 16; ++k) {
    int p = tid + k * 256;
    Sm[p] = S[(size_t)7 * RR + p];
  }
  __syncthreads();
  if (tid < 64) {
    double acc = 0.0;
    for (int c = 0; c < 64; ++c)
      acc = fma(cur[tid * 64 + c], Sm[c * 64 + tid], acc);
    tbuf[tid] = acc;
  }
  __syncthreads();
  if (tid == 0) {
    double tr = 0.0;
    for (int a = 0; a < 64; ++a) tr += tbuf[a];
    misc[0] = log(tr);
  }
}

// step 0 weights from RAW core (inline softplus)
__global__ __launch_bounds__(256) void k_w0(const float* __restrict__ raw,
                                            const double* __restrict__ head7,
                                            float* __restrict__ W) {
  const int tid = threadIdx.x;
  const int lane = tid & 63;
  const int n = blockIdx.x * 4 + (tid >> 6);
  const float* crow = raw + (size_t)n * RR;
  double acc = 0.0;
  for (int q = lane; q < RR; q += 64)
    acc = fma((double)softplus_fast(crow[q]), head7[(q & 63) * 64 + (q >> 6)], acc);
  for (int m = 32; m; m >>= 1) acc += __shfl_xor(acc, m);
  if (lane == 0) W[n] = (float)acc;
}

// FUSED: blocks 0..4095 = softplus(core_j)->Bh/Bl split;
//        blocks 4096..4607 = Mt build (MFMA w/ head, or direct transpose if !useHead)
__global__ __launch_bounds__(256) void k_spmt(const float* __restrict__ src,
                                              ushort* __restrict__ Bh,
                                              ushort* __restrict__ Bl,
                                              const float* __restrict__ tail,
                                              const double* __restrict__ head, int useHead,
                                              ushort* __restrict__ Ah,
                                              ushort* __restrict__ Al) {
  __shared__ alignas(16) float smem[4176];   // 16.7KB: mt2 hT(16KB) or mtid 64x65 f32
  const int bid = blockIdx.x, tid = threadIdx.x;
  if (bid < 4096) {
    // ---- softplus split path ----
    const size_t i4 = ((size_t)bid * 256 + tid) * 4;
    float4 v = *(const float4*)(src + i4);
    const float ov[4] = {softplus_fast(v.x), softplus_fast(v.y),
                         softplus_fast(v.z), softplus_fast(v.w)};
    ushort h4[4], l4[4];
#pragma unroll
    for (int q = 0; q < 4; ++q) {
      ushort h = f32_bf16(ov[q]);
      float hf = __uint_as_float((uint32_t)h << 16);
      h4[q] = h;
      l4[q] = f32_bf16(ov[q] - hf);
    }
    *(ushort4*)(Bh + i4) = make_ushort4(h4[0], h4[1], h4[2], h4[3]);
    *(ushort4*)(Bl + i4) = make_ushort4(l4[0], l4[1], l4[2], l4[3]);
    return;
  }
  const int blk = bid - 4096;   // 0..511
  if (useHead) {
    // ---- mt2: Mt[B,k*64+i] = sum_c tail[B,i,c]*head[c,k] via bf16 3-pass ----
    ushort (*hT)[4096] = (ushort(*)[4096])smem;
#pragma unroll
    for (int rep = 0; rep < 16; ++rep) {
      int i = tid + rep * 256;
      float v = (float)head[(i & 63) * 64 + (i >> 6)];
      ushort h = f32_bf16(v);
      float hf = __uint_as_float((uint32_t)h << 16);
      int dst = (i & 0xFC0) | (((((i >> 3) & 7) ^ ((i >> 6) & 7)) << 3)) | (i & 7);
      hT[0][dst] = h;
      hT[1][dst] = f32_bf16(v - hf);
    }
    __syncthreads();
    const int w = tid >> 6, l = tid & 63;
    const int B = blk * 4 + w;
    const float* tb = tail + (size_t)B * RR;
    const int lrow = l & 15, kg = l >> 4;
    ushort* ah_out = Ah + (size_t)B * RR;
    ushort* al_out = Al + (size_t)B * RR;
    for (int it = 0; it < 4; ++it) {
      BF8 afh[2], afl[2];
#pragma unroll
      for (int kt = 0; kt < 2; ++kt) {
        const float* s2 = tb + (it * 16 + lrow) * 64 + kt * 32 + kg * 8;
        float4 v0 = *(const float4*)s2;
        float4 v1 = *(const float4*)(s2 + 4);
        float vv[8] = {v0.x, v0.y, v0.z, v0.w, v1.x, v1.y, v1.z, v1.w};
#pragma unroll
        for (int q = 0; q < 8; ++q) {
          ushort h = f32_bf16(vv[q]);
          float hf = __uint_as_float((uint32_t)h << 16);
          afh[kt].u[q] = h;
          afl[kt].u[q] = f32_bf16(vv[q] - hf);
        }
      }
#pragma unroll
      for (int kt2 = 0; kt2 < 4; ++kt2) {
        f32x4 hh = (f32x4)0.0f, sm = (f32x4)0.0f;
#pragma unroll
        for (int kt = 0; kt < 2; ++kt) {
          int rowB = kt2 * 16 + lrow;
          int kcA  = kt * 4 + kg;
          int off  = rowB * 64 + ((kcA ^ (rowB & 7)) << 3);
          bf16x8 bh = *(const bf16x8*)&hT[0][off];
          bf16x8 bl = *(const bf16x8*)&hT[1][off];
          hh = __builtin_amdgcn_mfma_f32_16x16x32_bf16(afh[kt].v, bh, hh, 0, 0, 0);
          sm = __builtin_amdgcn_mfma_f32_16x16x32_bf16(afh[kt].v, bl, sm, 0, 0, 0);
          sm = __builtin_amdgcn_mfma_f32_16x16x32_bf16(afl[kt].v, bh, sm, 0, 0, 0);
        }
        ushort h4[4], l4[4];
#pragma unroll
        for (int q = 0; q < 4; ++q) {
          float v = hh[q] + sm[q];
          ushort h = f32_bf16(v);
          float hf = __uint_as_float((uint32_t)h << 16);
          h4[q] = h;
          l4[q] = f32_bf16(v - hf);
        }
        int o = (kt2 * 16 + lrow) * 64 + it * 16 + kg * 4;   // Mt = k*64 + i
        *(ushort4*)(ah_out + o) = make_ushort4(h4[0], h4[1], h4[2], h4[3]);
        *(ushort4*)(al_out + o) = make_ushort4(l4[0], l4[1], l4[2], l4[3]);
      }
    }
  } else {
    // ---- mtid: Mt[B,k*64+i] = tail[B,i,k] (head==I), pure transpose+split ----
    float* tl = smem;   // [64][65] padded
    for (int d = 0; d < 4; ++d) {
      const int B = blk * 4 + d;
      const float* tb = tail + (size_t)B * RR;
      ushort* ah_out = Ah + (size_t)B * RR;
      ushort* al_out = Al + (size_t)B * RR;
      __syncthreads();
#pragma unroll
      for (int r = 0; r < 4; ++r) {
        int p = tid * 4 + r * 1024;
        int i = p >> 6, k = p & 63;
        float4 v = *(const float4*)(tb + p);
        tl[i * 65 + k + 0] = v.x; tl[i * 65 + k + 1] = v.y;
        tl[i * 65 + k + 2] = v.z; tl[i * 65 + k + 3] = v.w;
      }
      __syncthreads();
#pragma unroll
      for (int r = 0; r < 4; ++r) {
        int p = tid * 4 + r * 1024;
        int k = p >> 6, i0 = p & 63;
        ushort h4[4], l4[4];
#pragma unroll
        for (int q = 0; q < 4; ++q) {
          float m = tl[(i0 + q) * 65 + k];
          ushort h = f32_bf16(m);
          float hf = __uint_as_float((uint32_t)h << 16);
          h4[q] = h;
          l4[q] = f32_bf16(m - hf);
        }
        *(ushort4*)(ah_out + p) = make_ushort4(h4[0], h4[1], h4[2], h4[3]);
        *(ushort4*)(al_out + p) = make_ushort4(l4[0], l4[1], l4[2], l4[3]);
      }
    }
  }
}

// Split-K x2 W-GEMM, 128x64 block tile (4 waves of 64x32 each).
// LDS 48KB single buffer: Ah[128][64] @0, Al @8192, Bh[64][64] @16384, Bl @20480.
// Same K order / pass structure / dump boundaries as r15 -> bit-identical W.
// FIX vs r16: B staging bases were missing the per-lane srow*RR term.
__global__ __launch_bounds__(256) void k_wgemm(const ushort* __restrict__ Ah,
                                               const ushort* __restrict__ Al,
                                               const ushort* __restrict__ Bh,
                                               const ushort* __restrict__ Bl,
                                               float* __restrict__ W) {
  __shared__ ushort lds[6 * 4096];     // 48KB
  const int tid = threadIdx.x;
  const int L = blockIdx.x;            // 0..511
  const int x = L & 7, j = L >> 3;     // xcd, seq
  const int half = j >> 5;             // K half
  const int j2 = j & 31;
  const int bn = (x & 1) * 8 + (j2 & 7);        // 0..15 (N tiles of 64)
  const int bm = (x >> 1) * 4 + (j2 >> 3);      // 0..15 (M tiles of 128)
  const int w = tid >> 6, l = tid & 63;

  const int srow = l >> 3;       // 0..7
  const int skc  = l & 7;
  // A staging: wave w -> array (w>>1: 0=Ah,1=Al), rows (w&1)*64 + q*8+srow
  const ushort* gbaseA = (w >= 2 ? Al : Ah) + (size_t)bm * 128 * RR
                       + (size_t)((w & 1) * 64 + srow) * RR
                       + (size_t)(((skc ^ srow)) * 8) + (size_t)half * 2048;
  // B staging: group g = w*4+q -> array (g>>3: 0=Bh,1=Bl), rows (g&7)*8+srow
  const ushort* gbaseB0 = Bh + (size_t)bn * 64 * RR + (size_t)srow * RR
                        + (size_t)(((skc ^ srow)) * 8) + (size_t)half * 2048;
  const ushort* gbaseB1 = Bl + (size_t)bn * 64 * RR + (size_t)srow * RR
                        + (size_t)(((skc ^ srow)) * 8) + (size_t)half * 2048;

  const int wm = (w >> 1) * 64, wn = (w & 1) * 32;
  const int lrow = l & 15;
  const int kg   = l >> 4;

  f32x4 acc_hh[4][2], acc_sm[4][2], hht[4][2];
#pragma unroll
  for (int mt = 0; mt < 4; ++mt)
#pragma unroll
    for (int nt = 0; nt < 2; ++nt) {
      acc_hh[mt][nt] = (f32x4)0.0f;
      acc_sm[mt][nt] = (f32x4)0.0f;
      hht[mt][nt]    = (f32x4)0.0f;
    }

  int roffA[4][2], roffB[2][2];
#pragma unroll
  for (int kt = 0; kt < 2; ++kt) {
    int kcA = kt * 4 + kg;
#pragma unroll
    for (int mt = 0; mt < 4; ++mt) {
      int rowA = wm + mt * 16 + lrow;              // 0..127
      roffA[mt][kt] = rowA * 64 + ((kcA ^ (rowA & 7)) << 3);
    }
#pragma unroll
    for (int nt = 0; nt < 2; ++nt) {
      int rowB = wn + nt * 16 + lrow;              // 0..63
      roffB[nt][kt] = 16384 + rowB * 64 + ((kcA ^ (rowB & 7)) << 3);
    }
  }

  for (int t = 0; t < 32; ++t) {
    const int koff = t * 64;
    __syncthreads();   // all waves done reading previous tile
#pragma unroll
    for (int q = 0; q < 8; ++q)    // A: 8 groups of 8 rows
      async_cp16(gbaseA + (size_t)q * 8 * RR + koff,
                 &lds[w * 4096 + q * 512]);
#pragma unroll
    for (int q = 0; q < 4; ++q) {  // B: 4 groups (g = w*4+q)
      const int g = w * 4 + q;
      const ushort* gb = (g >= 8 ? gbaseB1 : gbaseB0) + (size_t)((g & 7) * 8) * RR + koff;
      async_cp16(gb, &lds[16384 + g * 512]);
    }
    __syncthreads();   // drains vmcnt: tile landed
#pragma unroll
    for (int kt = 0; kt < 2; ++kt) {
      bf16x8 ah[4], al[4], bh[2], bl[2];
#pragma unroll
      for (int mt = 0; mt < 4; ++mt) {
        ah[mt] = *(const bf16x8*)&lds[0 * 8192 + roffA[mt][kt]];
        al[mt] = *(const bf16x8*)&lds[1 * 8192 + roffA[mt][kt]];
      }
#pragma unroll
      for (int nt = 0; nt < 2; ++nt) {
        bh[nt] = *(const bf16x8*)&lds[roffB[nt][kt]];
        bl[nt] = *(const bf16x8*)&lds[4096 + roffB[nt][kt]];
      }
#pragma unroll
      for (int mt = 0; mt < 4; ++mt)
#pragma unroll
        for (int nt = 0; nt < 2; ++nt) {
          acc_hh[mt][nt] = __builtin_amdgcn_mfma_f32_16x16x32_bf16(ah[mt], bh[nt], acc_hh[mt][nt], 0, 0, 0);
          acc_sm[mt][nt] = __builtin_amdgcn_mfma_f32_16x16x32_bf16(ah[mt], bl[nt], acc_sm[mt][nt], 0, 0, 0);
          acc_sm[mt][nt] = __builtin_amdgcn_mfma_f32_16x16x32_bf16(al[mt], bh[nt], acc_sm[mt][nt], 0, 0, 0);
        }
    }
    if ((t & 15) == 15) {   // chunk dump every 1024 k (same boundaries)
#pragma unroll
      for (int mt = 0; mt < 4; ++mt)
#pragma unroll
        for (int nt = 0; nt < 2; ++nt) {
          hht[mt][nt] += acc_hh[mt][nt];
          acc_hh[mt][nt] = (f32x4)0.0f;
        }
    }
  }

  float* Wout = W + (size_t)half * NDRAWS * D_CAT;
#pragma unroll
  for (int mt = 0; mt < 4; ++mt)
#pragma unroll
    for (int nt = 0; nt < 2; ++nt)
#pragma unroll
      for (int q = 0; q < 4; ++q) {
        int gr = bm * 128 + wm + mt * 16 + kg * 4 + q;
        int gc = bn * 64 + wn + nt * 16 + lrow;
        Wout[(size_t)gr * D_CAT + gc] = hht[mt][nt][q] + acc_sm[mt][nt][q];
      }
}

// FUSED sample + tail-update: one block per draw.
// Phase 1: gumbel-argmax; w = W row (shared, step0) or Wp0+Wp1 per-draw rows.
// Phase 2: tail[b] = C[m] @ tail[b] via MFMA 4-pass (or softplus-copy if first).
__global__ __launch_bounds__(256) void k_samptail(const float* __restrict__ W, int shared_row,
                                                  uint32_t key1, uint32_t key2,
                                                  float* __restrict__ out, int mode_j,
                                                  const float* __restrict__ raw,
                                                  const ushort* __restrict__ Bh,
                                                  const ushort* __restrict__ Bl,
                                                  float* __restrict__ tail, int first) {
  __shared__ float sv[4];
  __shared__ int   si[4];
  __shared__ int   s_m;
  __shared__ alignas(16) ushort Th[4096];
  __shared__ alignas(16) ushort Tl[4096];
  const int b = blockIdx.x, tid = threadIdx.x;

  // ---- phase 1: argmax(gumbel + log w) ----
  {
    const float* w0row = W + (shared_row ? 0 : (size_t)b * D_CAT);
    const float* w1row = W + (size_t)NDRAWS * D_CAT + (size_t)b * D_CAT;
    float best = -3.4e38f; int bidx = 0x7fffffff;
    for (int k = 0; k < 4; ++k) {
      int n = tid + k * 256;
      float wv = shared_row ? w0row[n] : (w0row[n] + w1row[n]);
      float lg = logf(fmaxf(wv, 1e-30f));
      float v = gumbel_at(key1, key2, (uint32_t)(b * D_CAT + n)) + lg;
      if (v > best || (v == best && n < bidx)) { best = v; bidx = n; }
    }
    for (int m = 32; m; m >>= 1) {
      float ov = __shfl_xor(best, m);
      int   oi = __shfl_xor(bidx, m);
      if (ov > best || (ov == best && oi < bidx)) { best = ov; bidx = oi; }
    }
    if ((tid & 63) == 0) { sv[tid >> 6] = best; si[tid >> 6] = bidx; }
    __syncthreads();
    if (tid == 0) {
      for (int t = 1; t < 4; ++t)
        if (sv[t] > best || (sv[t] == best && si[t] < bidx)) { best = sv[t]; bidx = si[t]; }
      s_m = bidx;
      out[b * KMODES + mode_j] = (float)bidx;
    }
    __syncthreads();
  }
  const int m = s_m;
  float* trow = tail + (size_t)b * RR;

  // ---- phase 2: tail update ----
  if (first) {
    const float* crow = raw + (size_t)m * RR;
#pragma unroll
    for (int r = 0; r < 4; ++r) {
      float4 v = *(const float4*)(crow + tid * 4 + r * 1024);
      float4 o;
      o.x = softplus_fast(v.x); o.y = softplus_fast(v.y);
      o.z = softplus_fast(v.z); o.w = softplus_fast(v.w);
      *(float4*)(trow + tid * 4 + r * 1024) = o;
    }
    return;
  }
  const ushort* ch = Bh + (size_t)m * RR;
  const ushort* cl = Bl + (size_t)m * RR;

  // transpose+split old tail into Th/Tl [k][c], chunk ^= (k&7)
#pragma unroll
  for (int r = 0; r < 4; ++r) {
    int p = tid * 4 + r * 1024;
    int i = p >> 6, k = p & 63;
    float4 v = *(const float4*)(trow + p);
    float vv[4] = {v.x, v.y, v.z, v.w};
#pragma unroll
    for (int q = 0; q < 4; ++q) {
      int row = k + q;
      int dst = row * 64 + ((((i >> 3) ^ (row & 7)) << 3)) + (i & 7);
      ushort h = f32_bf16(vv[q]);
      float hf = __uint_as_float((uint32_t)h << 16);
      Th[dst] = h;
      Tl[dst] = f32_bf16(vv[q] - hf);
    }
  }
  __syncthreads();

  const int w = tid >> 6, l = tid & 63;
  const int lrow = l & 15, kg = l >> 4;
  bf16x8 ah[2], al[2];
#pragma unroll
  for (int kt = 0; kt < 2; ++kt) {
    int off = (w * 16 + lrow) * 64 + kt * 32 + kg * 8;
    ah[kt] = *(const bf16x8*)(ch + off);
    al[kt] = *(const bf16x8*)(cl + off);
  }
#pragma unroll
  for (int jt = 0; jt < 4; ++jt) {
    f32x4 hh = (f32x4)0.0f, sm = (f32x4)0.0f;
#pragma unroll
    for (int kt = 0; kt < 2; ++kt) {
      int rowB = jt * 16 + lrow;
      int kcA  = kt * 4 + kg;
      int off  = rowB * 64 + ((kcA ^ (rowB & 7)) << 3);
      bf16x8 bh = *(const bf16x8*)&Th[off];
      bf16x8 bl = *(const bf16x8*)&Tl[off];
      hh = __builtin_amdgcn_mfma_f32_16x16x32_bf16(ah[kt], bh, hh, 0, 0, 0);
      sm = __builtin_amdgcn_mfma_f32_16x16x32_bf16(ah[kt], bl, sm, 0, 0, 0);
      sm = __builtin_amdgcn_mfma_f32_16x16x32_bf16(al[kt], bh, sm, 0, 0, 0);
      sm = __builtin_amdgcn_mfma_f32_16x16x32_bf16(al[kt], bl, sm, 0, 0, 0);  // ll
    }
#pragma unroll
    for (int q = 0; q < 4; ++q)
      trow[(w * 16 + kg * 4 + q) * 64 + jt * 16 + lrow] = hh[q] + sm[q];
  }
}

__global__ __launch_bounds__(256) void k_logp(const float* __restrict__ tail,
                                              const double* __restrict__ misc,
                                              float* __restrict__ out) {
  const int b = blockIdx.x * 256 + threadIdx.x;
  double tr = 0.0;
  for (int a = 0; a < 64; ++a) tr += (double)tail[(size_t)b * RR + a * 65];
  double lp = log(fmax(tr, 1e-30)) - misc[0];
  out[NDRAWS * KMODES + b] = (float)lp;
}

// ---------------- launcher ----------------
extern "C" void kernel_launch(void* const* d_in, const int* in_sizes, int n_in,
                              void* d_out, int out_size, void* d_ws, size_t ws_size,
                              hipStream_t stream) {
  (void)in_sizes; (void)n_in;
  CorePtrs cp;
  for (int i = 0; i < KMODES; ++i) cp.p[i] = (const float*)d_in[i];
  float* outf = (float*)d_out;

  char* base = (char*)d_ws;
  const size_t o_w     = 0;                                    // f32 2x 2048*1024 (split-K halves)
  const size_t o_tail  = o_w + (size_t)2 * NDRAWS * D_CAT * 4; // f32 2048*4096
  const size_t o_ahl   = o_tail + (size_t)NDRAWS * RR * 4;     // u16 Ah+Al (2x 2048*4096)
  const size_t o_spart = o_ahl;                                // f32 2048*4096 (prologue only)
  const size_t o_S     = o_ahl + (size_t)NDRAWS * RR * 4;      // f64 8*4096
  const size_t o_heads = o_S + (size_t)KMODES * RR * 8;        // f64 7*4096
  const size_t o_misc  = o_heads + (size_t)7 * RR * 8;         // f64 lognorm
  const size_t o_bh    = o_misc + 256;                         // u16 1024*4096
  const size_t o_bl    = o_bh + (size_t)D_CAT * RR * 2;        // u16 1024*4096
  const size_t NEED    = o_bl + (size_t)D_CAT * RR * 2;
  if (ws_size < NEED) {
    k_sentinel<<<(out_size + 255) / 256, 256, 0, stream>>>(outf, out_size);
    return;
  }

  float*  W     = (float*)(base + o_w);
  float*  tail  = (float*)(base + o_tail);
  ushort* Ah    = (ushort*)(base + o_ahl);
  ushort* Al    = Ah + (size_t)NDRAWS * RR;
  float*  Spart = (float*)(base + o_spart);
  double* S     = (double*)(base + o_S);
  double* heads = (double*)(base + o_heads);
  double* misc  = (double*)(base + o_misc);
  ushort* Bh    = (ushort*)(base + o_bh);
  ushort* Bl    = (ushort*)(base + o_bl);

  // keys[s] = threefry2x32((0,1), (0,s))  -- split(key(1), 8), foldlike
  uint32_t kk1[KMODES], kk2[KMODES];
  for (uint32_t s = 0; s < KMODES; ++s) tf2x32(0u, 1u, 0u, s, kk1[s], kk2[s]);

  k_spart  <<<2048, 256, 0, stream>>>(cp, Spart);
  k_sreduce<<<128,  256, 0, stream>>>(Spart, S);
  k_heads  <<<1,    256, 0, stream>>>(S, heads, misc);

  for (int s = 0; s < KMODES; ++s) {
    const int j = 7 - s;
    if (s == 0) {
      k_w0<<<256, 256, 0, stream>>>(cp.p[7], heads + (size_t)6 * RR, W);
    } else {
      k_spmt<<<4608, 256, 0, stream>>>(cp.p[j], Bh, Bl, tail,
                                       j > 0 ? heads + (size_t)(j - 1) * RR : heads,
                                       j > 0 ? 1 : 0, Ah, Al);
      k_wgemm<<<512, 256, 0, stream>>>(Ah, Al, Bh, Bl, W);
    }
    k_samptail<<<NDRAWS, 256, 0, stream>>>(W, s == 0 ? 1 : 0, kk1[s], kk2[s],
                                           outf, j, cp.p[j], Bh, Bl, tail,
                                           s == 0 ? 1 : 0);
  }
  k_logp<<<KMODES, 256, 0, stream>>>(tail, misc, outf);
}